// Round 3
// baseline (2160.875 us; speedup 1.0000x reference)
//
#include <hip/hip_runtime.h>
#include <math.h>

#define NB    16      // batch
#define CDIM  256
#define COUT  144     // 64 q + 16 k + 64 v
#define MPIX  4096    // 64*64
#define DIMK  16
#define NHEADS 4
#define DIMV  64
#define SCOPE 23
#define PADH  11
#define BNEPS 1e-5f

// ---------------- K1: qkv = w_qkv @ x  (per batch: 144x256 @ 256x4096) ----------------
__global__ void __launch_bounds__(256) gemm_qkv(const float* __restrict__ x,
                                                const float* __restrict__ w,
                                                float* __restrict__ qkv) {
    __shared__ float xs[32][256];
    __shared__ float wsb[48][33];
    int mt = blockIdx.x, ot = blockIdx.y, b = blockIdx.z;
    int m0 = mt * 256, o0 = ot * 48;
    int tid = threadIdx.x;
    int to = tid >> 6;   // 0..3
    int tm = tid & 63;   // 0..63
    float acc[12][4];
#pragma unroll
    for (int i = 0; i < 12; i++)
#pragma unroll
        for (int j = 0; j < 4; j++) acc[i][j] = 0.f;

    const float* xb = x + (size_t)b * CDIM * MPIX;
    for (int k0 = 0; k0 < CDIM; k0 += 32) {
        __syncthreads();
#pragma unroll
        for (int i = 0; i < 32; i++)
            xs[i][tid] = xb[(size_t)(k0 + i) * MPIX + m0 + tid];
#pragma unroll
        for (int i = 0; i < 6; i++) {
            int idx = i * 256 + tid;
            int o = idx >> 5, r = idx & 31;
            wsb[o][r] = w[(size_t)(o0 + o) * CDIM + k0 + r];
        }
        __syncthreads();
#pragma unroll 4
        for (int r = 0; r < 32; r++) {
            float4 xv = *(const float4*)&xs[r][tm * 4];
#pragma unroll
            for (int i = 0; i < 12; i++) {
                float wv = wsb[to * 12 + i][r];
                acc[i][0] = fmaf(wv, xv.x, acc[i][0]);
                acc[i][1] = fmaf(wv, xv.y, acc[i][1]);
                acc[i][2] = fmaf(wv, xv.z, acc[i][2]);
                acc[i][3] = fmaf(wv, xv.w, acc[i][3]);
            }
        }
    }
#pragma unroll
    for (int i = 0; i < 12; i++) {
        float4 v = make_float4(acc[i][0], acc[i][1], acc[i][2], acc[i][3]);
        *(float4*)&qkv[((size_t)b * COUT + o0 + to * 12 + i) * MPIX + m0 + tm * 4] = v;
    }
}

// ---------------- K2: BN partial sums per (channel, batch) ----------------
__global__ void stats_partial(const float* __restrict__ qkv, float* __restrict__ part) {
    int ch = blockIdx.x, b = blockIdx.y;
    int o = (ch < 64) ? ch : (80 + ch - 64);
    const float* row = qkv + ((size_t)b * COUT + o) * MPIX;
    int tid = threadIdx.x;
    float s = 0.f, s2 = 0.f;
    for (int i = tid; i < MPIX; i += 256) {
        float v = row[i];
        s += v;
        s2 = fmaf(v, v, s2);
    }
#pragma unroll
    for (int off = 32; off > 0; off >>= 1) {
        s += __shfl_down(s, off);
        s2 += __shfl_down(s2, off);
    }
    __shared__ float red[8];
    int wid = tid >> 6, lane = tid & 63;
    if (lane == 0) { red[wid * 2] = s; red[wid * 2 + 1] = s2; }
    __syncthreads();
    if (tid == 0) {
        float ts = 0.f, ts2 = 0.f;
#pragma unroll
        for (int w2 = 0; w2 < 4; w2++) { ts += red[w2 * 2]; ts2 += red[w2 * 2 + 1]; }
        part[(size_t)(ch * 16 + b) * 2 + 0] = ts;
        part[(size_t)(ch * 16 + b) * 2 + 1] = ts2;
    }
}

// ---------------- K3: finalize scale/shift ----------------
__global__ void stats_finalize(const float* __restrict__ part,
                               const float* __restrict__ gq, const float* __restrict__ bq,
                               const float* __restrict__ gv, const float* __restrict__ bv,
                               float* __restrict__ ascale, float* __restrict__ dshift) {
    int ch = threadIdx.x;
    if (ch >= 128) return;
    float s = 0.f, s2 = 0.f;
    for (int b = 0; b < 16; b++) {
        s += part[(size_t)(ch * 16 + b) * 2 + 0];
        s2 += part[(size_t)(ch * 16 + b) * 2 + 1];
    }
    const float invN = 1.0f / 65536.0f;
    float mean = s * invN;
    float var = s2 * invN - mean * mean;
    float g = (ch < 64) ? gq[ch] : gv[ch - 64];
    float be = (ch < 64) ? bq[ch] : bv[ch - 64];
    float a = g * rsqrtf(var + BNEPS);
    ascale[ch] = a;
    dshift[ch] = be - mean * a;
}

// ---------------- K4: softmax over m for each (b, kc) ----------------
__global__ void softmax_k(const float* __restrict__ qkv, float* __restrict__ p) {
    int bk = blockIdx.x;
    int b = bk >> 4, kc = bk & 15;
    const float* row = qkv + ((size_t)b * COUT + 64 + kc) * MPIX;
    int tid = threadIdx.x;
    float v[16];
    float mx = -INFINITY;
#pragma unroll
    for (int i = 0; i < 16; i++) {
        v[i] = row[tid + i * 256];
        mx = fmaxf(mx, v[i]);
    }
#pragma unroll
    for (int off = 32; off > 0; off >>= 1) mx = fmaxf(mx, __shfl_down(mx, off));
    __shared__ float redm[4];
    __shared__ float bm;
    int wid = tid >> 6, lane = tid & 63;
    if (lane == 0) redm[wid] = mx;
    __syncthreads();
    if (tid == 0) bm = fmaxf(fmaxf(redm[0], redm[1]), fmaxf(redm[2], redm[3]));
    __syncthreads();
    mx = bm;
    float s = 0.f;
#pragma unroll
    for (int i = 0; i < 16; i++) {
        v[i] = expf(v[i] - mx);
        s += v[i];
    }
#pragma unroll
    for (int off = 32; off > 0; off >>= 1) s += __shfl_down(s, off);
    __shared__ float reds[4];
    __shared__ float bs;
    if (lane == 0) reds[wid] = s;
    __syncthreads();
    if (tid == 0) bs = reds[0] + reds[1] + reds[2] + reds[3];
    __syncthreads();
    float r = 1.0f / bs;
    float* prow = p + ((size_t)b * 16 + kc) * MPIX;
#pragma unroll
    for (int i = 0; i < 16; i++) prow[tid + i * 256] = v[i] * r;
}

// ---------------- K5: content lambda partials ----------------
__global__ void cl_partial(const float* __restrict__ qkv, const float* __restrict__ p,
                           const float* __restrict__ ascale, const float* __restrict__ dshift,
                           float* __restrict__ clpart) {
    __shared__ float vsT[128][65];
    int mc = blockIdx.x, b = blockIdx.y;
    int m0 = mc * 256;
    int tid = threadIdx.x;
    int vc = tid & 63, kg = tid >> 6;
    float acc[4] = {0.f, 0.f, 0.f, 0.f};
    for (int half = 0; half < 2; half++) {
        int mh = m0 + half * 128;
        __syncthreads();
        for (int i = tid; i < 64 * 128; i += 256) {
            int r = i >> 7, c = i & 127;
            vsT[c][r] = fmaf(ascale[64 + r], qkv[((size_t)b * COUT + 80 + r) * MPIX + mh + c],
                             dshift[64 + r]);
        }
        __syncthreads();
        for (int mm = 0; mm < 128; mm++) {
            float vv = vsT[mm][vc];
#pragma unroll
            for (int i = 0; i < 4; i++) {
                int kc = kg * 4 + i;
                acc[i] = fmaf(p[((size_t)b * 16 + kc) * MPIX + mh + mm], vv, acc[i]);
            }
        }
    }
#pragma unroll
    for (int i = 0; i < 4; i++) {
        int kc = kg * 4 + i;
        clpart[(((size_t)b * 16 + mc) * 16 + kc) * 64 + vc] = acc[i];
    }
}

__global__ void cl_reduce(const float* __restrict__ clpart, float* __restrict__ cl) {
    int b = blockIdx.x;
    for (int o = threadIdx.x; o < 1024; o += 256) {
        float s = 0.f;
        for (int mc = 0; mc < 16; mc++)
            s += clpart[((size_t)b * 16 + mc) * 1024 + o];
        cl[(size_t)b * 1024 + o] = s;
    }
}

// ---------------- K6: permute lconv weights to [tap][k] ----------------
__global__ void permute_w(const float* __restrict__ wl, float* __restrict__ wp) {
    int i = blockIdx.x * 256 + threadIdx.x;
    if (i < 16 * 529) {
        int k = i / 529, t = i - k * 529;
        wp[t * 16 + k] = wl[i];
    }
}

// ---------------- K7: fused 23x23 conv + lambda epilogue ----------------
// grid (64 vc, 16 b), block 256.
// Wave = one full 64-wide row (lane x = tid&63, conflict-free b32 LDS reads).
// Image staged in 2 vertical halves (54 rows x 88) -> LDS 53.4 KB -> 3 blocks/CU.
// Weights LDS-resident [tap][k], read as uniform-address ds_read_b128 (broadcast).
#define SVW 88
__global__ void __launch_bounds__(256) lambda_main(
    const float* __restrict__ qkv, const float* __restrict__ ascale,
    const float* __restrict__ dshift, const float* __restrict__ cl,
    const float* __restrict__ wp, const float* __restrict__ bl,
    float* __restrict__ out) {
    __shared__ float sw[529 * 16];     // 33,856 B  [tap][k]
    __shared__ float sv[54 * SVW];     // 19,008 B  half-image with halo
    __shared__ float sck[16];
    __shared__ float saq[64], sdq[64];

    int vc = blockIdx.x, b = blockIdx.y;
    int tid = threadIdx.x;

    for (int i = tid; i < 529 * 16; i += 256) sw[i] = wp[i];
    if (tid < 64) { saq[tid] = ascale[tid]; sdq[tid] = dshift[tid]; }
    if (tid >= 64 && tid < 80) {
        int k = tid - 64;
        sck[k] = cl[((size_t)b * 16 + k) * 64 + vc] + bl[k];
    }

    float av = ascale[64 + vc], dv = dshift[64 + vc];
    const float* vrow = qkv + ((size_t)b * COUT + 80 + vc) * MPIX;
    const float* qb = qkv + (size_t)b * COUT * MPIX;
    float* ob = out + (size_t)b * 256 * MPIX;

    int x = tid & 63;        // lane x: full-row coverage, coalesced/conflict-free
    int ly0 = tid >> 6;      // wave row 0..3

#pragma unroll 1
    for (int h = 0; h < 2; h++) {
        // stage padded rows h*32 .. h*32+53
        for (int i = tid; i < 54 * SVW; i += 256) {
            int yy = i / SVW, xx = i - yy * SVW;
            int iy = h * 32 + yy - PADH, ix = xx - PADH;
            float val = 0.f;
            if ((unsigned)iy < 64u && (unsigned)ix < 64u)
                val = fmaf(av, vrow[iy * 64 + ix], dv);
            sv[i] = val;
        }
        __syncthreads();

#pragma unroll 1
        for (int pass = 0; pass < 2; pass++) {
            // this pass covers local rows pass*16 + ly0 + 4j (j=0..3)
            int lr = pass * 16 + ly0;
            float acc[16][4];
#pragma unroll
            for (int k = 0; k < 16; k++)
#pragma unroll
                for (int j = 0; j < 4; j++) acc[k][j] = 0.f;

#pragma unroll 1
            for (int dy = 0; dy < 23; dy++) {
                const float* svp = &sv[(lr + dy) * SVW + x];
                const float* wt = &sw[dy * 23 * 16];
#pragma unroll
                for (int dx = 0; dx < 23; dx++) {
                    float vv[4];
#pragma unroll
                    for (int j = 0; j < 4; j++) vv[j] = svp[j * 4 * SVW + dx];
#pragma unroll
                    for (int kk = 0; kk < 4; kk++) {
                        float4 w4 = *(const float4*)&wt[dx * 16 + kk * 4];  // uniform -> broadcast
#pragma unroll
                        for (int j = 0; j < 4; j++) {
                            acc[kk * 4 + 0][j] = fmaf(w4.x, vv[j], acc[kk * 4 + 0][j]);
                            acc[kk * 4 + 1][j] = fmaf(w4.y, vv[j], acc[kk * 4 + 1][j]);
                            acc[kk * 4 + 2][j] = fmaf(w4.z, vv[j], acc[kk * 4 + 2][j]);
                            acc[kk * 4 + 3][j] = fmaf(w4.w, vv[j], acc[kk * 4 + 3][j]);
                        }
                    }
                }
            }

            // epilogue: out[b, n*64+vc, m] = sum_k q_bn[k*4+n, m] * (sck[k] + pl[k,m])
#pragma unroll 1
            for (int j = 0; j < 4; j++) {
                int m = (h * 32 + pass * 16 + ly0 + 4 * j) * 64 + x;
                float o0 = 0.f, o1 = 0.f, o2 = 0.f, o3 = 0.f;
#pragma unroll
                for (int k = 0; k < 16; k++) {
                    float lam = sck[k] + acc[k][j];
                    int c = k * 4;
                    float q0 = fmaf(saq[c + 0], qb[(size_t)(c + 0) * MPIX + m], sdq[c + 0]);
                    float q1 = fmaf(saq[c + 1], qb[(size_t)(c + 1) * MPIX + m], sdq[c + 1]);
                    float q2 = fmaf(saq[c + 2], qb[(size_t)(c + 2) * MPIX + m], sdq[c + 2]);
                    float q3 = fmaf(saq[c + 3], qb[(size_t)(c + 3) * MPIX + m], sdq[c + 3]);
                    o0 = fmaf(q0, lam, o0);
                    o1 = fmaf(q1, lam, o1);
                    o2 = fmaf(q2, lam, o2);
                    o3 = fmaf(q3, lam, o3);
                }
                ob[(size_t)(0 * 64 + vc) * MPIX + m] = o0;
                ob[(size_t)(1 * 64 + vc) * MPIX + m] = o1;
                ob[(size_t)(2 * 64 + vc) * MPIX + m] = o2;
                ob[(size_t)(3 * 64 + vc) * MPIX + m] = o3;
            }
        }
        __syncthreads();   // all waves done with this half before restage
    }
}

// ---------------- launch ----------------
extern "C" void kernel_launch(void* const* d_in, const int* in_sizes, int n_in,
                              void* d_out, int out_size, void* d_ws, size_t ws_size,
                              hipStream_t stream) {
    const float* x      = (const float*)d_in[0];
    const float* w_qkv  = (const float*)d_in[1];
    const float* gq     = (const float*)d_in[2];
    const float* bq     = (const float*)d_in[3];
    const float* gv     = (const float*)d_in[4];
    const float* bv     = (const float*)d_in[5];
    const float* wl     = (const float*)d_in[6];
    const float* bl     = (const float*)d_in[7];
    float* out = (float*)d_out;

    float* ws     = (float*)d_ws;
    float* qkv    = ws;                    // 16*144*4096 = 9,437,184
    float* p      = qkv + 9437184;         // 16*16*4096  = 1,048,576
    float* part   = p + 1048576;           // 128*16*2    = 4,096
    float* ascale = part + 4096;           // 128
    float* dshift = ascale + 128;          // 128
    float* clpart = dshift + 128;          // 16*16*16*64 = 262,144
    float* clb    = clpart + 262144;       // 16*16*64    = 16,384
    float* wpb    = clb + 16384;           // 529*16      = 8,464

    gemm_qkv<<<dim3(16, 3, 16), 256, 0, stream>>>(x, w_qkv, qkv);
    stats_partial<<<dim3(128, 16), 256, 0, stream>>>(qkv, part);
    stats_finalize<<<1, 128, 0, stream>>>(part, gq, bq, gv, bv, ascale, dshift);
    softmax_k<<<256, 256, 0, stream>>>(qkv, p);
    cl_partial<<<dim3(16, 16), 256, 0, stream>>>(qkv, p, ascale, dshift, clpart);
    cl_reduce<<<16, 256, 0, stream>>>(clpart, clb);
    permute_w<<<34, 256, 0, stream>>>(wl, wpb);
    lambda_main<<<dim3(64, 16), 256, 0, stream>>>(qkv, ascale, dshift, clb, wpb, bl, out);
}

// Round 4
// 479.950 us; speedup vs baseline: 4.5023x; 4.5023x over previous
//
#include <hip/hip_runtime.h>
#include <math.h>

#define NB    16      // batch
#define CDIM  256
#define COUT  144     // 64 q + 16 k + 64 v
#define MPIX  4096    // 64*64
#define SCOPE 23
#define PADH  11
#define BNEPS 1e-5f

typedef __attribute__((ext_vector_type(4))) float f32x4;
typedef __attribute__((ext_vector_type(8))) short s16x8;

__device__ __forceinline__ unsigned short f2bf(float f) {
    unsigned u = __builtin_bit_cast(unsigned, f);
    unsigned r = (u + 0x7FFFu + ((u >> 16) & 1u)) >> 16;
    return (unsigned short)r;
}
__device__ __forceinline__ float bf2f(unsigned short s) {
    unsigned u = ((unsigned)s) << 16;
    return __builtin_bit_cast(float, u);
}

// ---------------- K1: qkv = w_qkv @ x  (per batch: 144x256 @ 256x4096) ----------------
__global__ void __launch_bounds__(256) gemm_qkv(const float* __restrict__ x,
                                                const float* __restrict__ w,
                                                float* __restrict__ qkv) {
    __shared__ float xs[32][256];
    __shared__ float wsb[48][33];
    int mt = blockIdx.x, ot = blockIdx.y, b = blockIdx.z;
    int m0 = mt * 256, o0 = ot * 48;
    int tid = threadIdx.x;
    int to = tid >> 6;
    int tm = tid & 63;
    float acc[12][4];
#pragma unroll
    for (int i = 0; i < 12; i++)
#pragma unroll
        for (int j = 0; j < 4; j++) acc[i][j] = 0.f;

    const float* xb = x + (size_t)b * CDIM * MPIX;
    for (int k0 = 0; k0 < CDIM; k0 += 32) {
        __syncthreads();
#pragma unroll
        for (int i = 0; i < 32; i++)
            xs[i][tid] = xb[(size_t)(k0 + i) * MPIX + m0 + tid];
#pragma unroll
        for (int i = 0; i < 6; i++) {
            int idx = i * 256 + tid;
            int o = idx >> 5, r = idx & 31;
            wsb[o][r] = w[(size_t)(o0 + o) * CDIM + k0 + r];
        }
        __syncthreads();
#pragma unroll 4
        for (int r = 0; r < 32; r++) {
            float4 xv = *(const float4*)&xs[r][tm * 4];
#pragma unroll
            for (int i = 0; i < 12; i++) {
                float wv = wsb[to * 12 + i][r];
                acc[i][0] = fmaf(wv, xv.x, acc[i][0]);
                acc[i][1] = fmaf(wv, xv.y, acc[i][1]);
                acc[i][2] = fmaf(wv, xv.z, acc[i][2]);
                acc[i][3] = fmaf(wv, xv.w, acc[i][3]);
            }
        }
    }
#pragma unroll
    for (int i = 0; i < 12; i++) {
        float4 v = make_float4(acc[i][0], acc[i][1], acc[i][2], acc[i][3]);
        *(float4*)&qkv[((size_t)b * COUT + o0 + to * 12 + i) * MPIX + m0 + tm * 4] = v;
    }
}

// ---------------- K2: BN partial sums per (channel, batch) ----------------
__global__ void stats_partial(const float* __restrict__ qkv, float* __restrict__ part) {
    int ch = blockIdx.x, b = blockIdx.y;
    int o = (ch < 64) ? ch : (80 + ch - 64);
    const float* row = qkv + ((size_t)b * COUT + o) * MPIX;
    int tid = threadIdx.x;
    float s = 0.f, s2 = 0.f;
    for (int i = tid; i < MPIX; i += 256) {
        float v = row[i];
        s += v;
        s2 = fmaf(v, v, s2);
    }
#pragma unroll
    for (int off = 32; off > 0; off >>= 1) {
        s += __shfl_down(s, off);
        s2 += __shfl_down(s2, off);
    }
    __shared__ float red[8];
    int wid = tid >> 6, lane = tid & 63;
    if (lane == 0) { red[wid * 2] = s; red[wid * 2 + 1] = s2; }
    __syncthreads();
    if (tid == 0) {
        float ts = 0.f, ts2 = 0.f;
#pragma unroll
        for (int w2 = 0; w2 < 4; w2++) { ts += red[w2 * 2]; ts2 += red[w2 * 2 + 1]; }
        part[(size_t)(ch * 16 + b) * 2 + 0] = ts;
        part[(size_t)(ch * 16 + b) * 2 + 1] = ts2;
    }
}

// ---------------- K3: finalize scale/shift ----------------
__global__ void stats_finalize(const float* __restrict__ part,
                               const float* __restrict__ gq, const float* __restrict__ bq,
                               const float* __restrict__ gv, const float* __restrict__ bv,
                               float* __restrict__ ascale, float* __restrict__ dshift) {
    int ch = threadIdx.x;
    if (ch >= 128) return;
    float s = 0.f, s2 = 0.f;
    for (int b = 0; b < 16; b++) {
        s += part[(size_t)(ch * 16 + b) * 2 + 0];
        s2 += part[(size_t)(ch * 16 + b) * 2 + 1];
    }
    const float invN = 1.0f / 65536.0f;
    float mean = s * invN;
    float var = s2 * invN - mean * mean;
    float g = (ch < 64) ? gq[ch] : gv[ch - 64];
    float be = (ch < 64) ? bq[ch] : bv[ch - 64];
    float a = g * rsqrtf(var + BNEPS);
    ascale[ch] = a;
    dshift[ch] = be - mean * a;
}

// ---------------- K4: softmax over m for each (b, kc) ----------------
__global__ void softmax_k(const float* __restrict__ qkv, float* __restrict__ p) {
    int bk = blockIdx.x;
    int b = bk >> 4, kc = bk & 15;
    const float* row = qkv + ((size_t)b * COUT + 64 + kc) * MPIX;
    int tid = threadIdx.x;
    float v[16];
    float mx = -INFINITY;
#pragma unroll
    for (int i = 0; i < 16; i++) {
        v[i] = row[tid + i * 256];
        mx = fmaxf(mx, v[i]);
    }
#pragma unroll
    for (int off = 32; off > 0; off >>= 1) mx = fmaxf(mx, __shfl_down(mx, off));
    __shared__ float redm[4];
    __shared__ float bm;
    int wid = tid >> 6, lane = tid & 63;
    if (lane == 0) redm[wid] = mx;
    __syncthreads();
    if (tid == 0) bm = fmaxf(fmaxf(redm[0], redm[1]), fmaxf(redm[2], redm[3]));
    __syncthreads();
    mx = bm;
    float s = 0.f;
#pragma unroll
    for (int i = 0; i < 16; i++) {
        v[i] = expf(v[i] - mx);
        s += v[i];
    }
#pragma unroll
    for (int off = 32; off > 0; off >>= 1) s += __shfl_down(s, off);
    __shared__ float reds[4];
    __shared__ float bs;
    if (lane == 0) reds[wid] = s;
    __syncthreads();
    if (tid == 0) bs = reds[0] + reds[1] + reds[2] + reds[3];
    __syncthreads();
    float r = 1.0f / bs;
    float* prow = p + ((size_t)b * 16 + kc) * MPIX;
#pragma unroll
    for (int i = 0; i < 16; i++) prow[tid + i * 256] = v[i] * r;
}

// ---------------- K5: content lambda partials ----------------
__global__ void cl_partial(const float* __restrict__ qkv, const float* __restrict__ p,
                           const float* __restrict__ ascale, const float* __restrict__ dshift,
                           float* __restrict__ clpart) {
    __shared__ float vsT[128][65];
    int mc = blockIdx.x, b = blockIdx.y;
    int m0 = mc * 256;
    int tid = threadIdx.x;
    int vc = tid & 63, kg = tid >> 6;
    float acc[4] = {0.f, 0.f, 0.f, 0.f};
    for (int half = 0; half < 2; half++) {
        int mh = m0 + half * 128;
        __syncthreads();
        for (int i = tid; i < 64 * 128; i += 256) {
            int r = i >> 7, c = i & 127;
            vsT[c][r] = fmaf(ascale[64 + r], qkv[((size_t)b * COUT + 80 + r) * MPIX + mh + c],
                             dshift[64 + r]);
        }
        __syncthreads();
        for (int mm = 0; mm < 128; mm++) {
            float vv = vsT[mm][vc];
#pragma unroll
            for (int i = 0; i < 4; i++) {
                int kc = kg * 4 + i;
                acc[i] = fmaf(p[((size_t)b * 16 + kc) * MPIX + mh + mm], vv, acc[i]);
            }
        }
    }
#pragma unroll
    for (int i = 0; i < 4; i++) {
        int kc = kg * 4 + i;
        clpart[(((size_t)b * 16 + mc) * 16 + kc) * 64 + vc] = acc[i];
    }
}

__global__ void cl_reduce(const float* __restrict__ clpart, float* __restrict__ cl) {
    int b = blockIdx.x;
    for (int o = threadIdx.x; o < 1024; o += 256) {
        float s = 0.f;
        for (int mc = 0; mc < 16; mc++)
            s += clpart[((size_t)b * 16 + mc) * 1024 + o];
        cl[(size_t)b * 1024 + o] = s;
    }
}

// ---------------- K6: apply BN to q channels in-place (q = ch 0..63 of qkv) ----------------
__global__ void bn_q(float* __restrict__ qkv, const float* __restrict__ ascale,
                     const float* __restrict__ dshift) {
    int c = blockIdx.x, b = blockIdx.y;
    float a = ascale[c], d = dshift[c];
    float4* p = (float4*)(qkv + ((size_t)b * COUT + c) * MPIX);
    for (int i = threadIdx.x; i < 1024; i += 256) {
        float4 v = p[i];
        v.x = fmaf(a, v.x, d);
        v.y = fmaf(a, v.y, d);
        v.z = fmaf(a, v.z, d);
        v.w = fmaf(a, v.w, d);
        p[i] = v;
    }
}

// ---------------- K7: build MFMA A-fragments of lconv weights (bf16 hi/lo split) --------
// layout: wfrag[((dy*2 + pass)*64 + lane)*8 + j], lane -> k = lane&15, tap = (lane>>4)*8 + j
__global__ void wfrag_prep(const float* __restrict__ wl, short* __restrict__ wfrag) {
    int i = blockIdx.x * 256 + threadIdx.x;
    if (i >= 23 * 2 * 64 * 8) return;
    int j = i & 7, l = (i >> 3) & 63, pass = (i >> 9) & 1, dy = i >> 10;
    int k = l & 15, t = ((l >> 4) << 3) + j;
    float w = (t < SCOPE) ? wl[k * 529 + dy * 23 + t] : 0.f;
    unsigned short hi = f2bf(w);
    unsigned short res = pass ? f2bf(w - bf2f(hi)) : hi;
    wfrag[i] = (short)res;
}

// ---------------- K8: fused MFMA conv + lambda epilogue ----------------
// grid (64 vc, 16 b), block 256 (4 waves). Per wave: 4 row-groups of 4 image rows;
// per group: acc[16] m-tiles (16x16), K-loop over 23 dy rows, 2 MFMAs (w_hi,w_lo) per tile.
// Image in LDS as overlapping bf16-pair dwords: spack[e] = (bf16 v[e], bf16 v[e+1]).
#define SPW 88
__global__ void __launch_bounds__(256, 4) lambda_main(
    const float* __restrict__ qkv, const float* __restrict__ ascale,
    const float* __restrict__ dshift, const float* __restrict__ cl,
    const short* __restrict__ wfrag, const float* __restrict__ bl,
    float* __restrict__ out) {
    __shared__ unsigned spack[86 * SPW + 8];
    __shared__ float sck[16];

    int vc = blockIdx.x, b = blockIdx.y;
    int tid = threadIdx.x;

    if (tid < 16) sck[tid] = cl[((size_t)b * 16 + tid) * 64 + vc] + bl[tid];

    float av = ascale[64 + vc], dv = dshift[64 + vc];
    const float* vrow = qkv + ((size_t)b * COUT + 80 + vc) * MPIX;
    for (int i = tid; i < 86 * SPW; i += 256) {
        int y = i / SPW, e = i - y * SPW;
        int iy = y - PADH;
        float f0 = 0.f, f1 = 0.f;
        if ((unsigned)iy < 64u) {
            int ix0 = e - PADH, ix1 = e - PADH + 1;
            if ((unsigned)ix0 < 64u) f0 = fmaf(av, vrow[iy * 64 + ix0], dv);
            if ((unsigned)ix1 < 64u) f1 = fmaf(av, vrow[iy * 64 + ix1], dv);
        }
        spack[i] = (unsigned)f2bf(f0) | ((unsigned)f2bf(f1) << 16);
    }
    if (tid < 8) spack[86 * SPW + tid] = 0u;
    __syncthreads();

    int lane = tid & 63;
    int wv = tid >> 6;          // wave 0..3
    int px = lane & 15;         // MFMA N-col = pixel
    int kg = lane >> 4;         // K-chunk group / C-row group
    const s16x8* wf = (const s16x8*)wfrag;

    const float* qslab = qkv + (size_t)b * COUT * MPIX;   // q channels (BN'd by bn_q)
    float* ob = out + (size_t)b * 256 * MPIX;

    float sck_l[4];
#pragma unroll
    for (int r = 0; r < 4; r++) sck_l[r] = sck[kg * 4 + r];

#pragma unroll 1
    for (int gg = 0; gg < 4; gg++) {
        int y0 = (gg * 4 + wv) * 4;          // this wave's 4 image rows
        f32x4 acc[16];
#pragma unroll
        for (int t = 0; t < 16; t++) acc[t] = 0.f;

#pragma unroll 1
        for (int dy = 0; dy < 23; dy++) {
            s16x8 wa = wf[(dy * 2 + 0) * 64 + lane];
            s16x8 wb = wf[(dy * 2 + 1) * 64 + lane];
#pragma unroll
            for (int ty = 0; ty < 4; ty++) {
                const unsigned* pr = &spack[(y0 + ty + dy) * SPW + px + kg * 8];
#pragma unroll
                for (int xt = 0; xt < 4; xt++) {
                    const unsigned* p = pr + xt * 16;
                    int4 bi = make_int4(p[0], p[2], p[4], p[6]);  // 2x ds_read2_b32
                    s16x8 bf = __builtin_bit_cast(s16x8, bi);
                    int t = ty * 4 + xt;
                    acc[t] = __builtin_amdgcn_mfma_f32_16x16x32_bf16(wa, bf, acc[t], 0, 0, 0);
                    acc[t] = __builtin_amdgcn_mfma_f32_16x16x32_bf16(wb, bf, acc[t], 0, 0, 0);
                }
            }
        }

        // epilogue: lane holds pl[kf = kg*4+r][px] for its 16-px tile
#pragma unroll
        for (int t = 0; t < 16; t++) {
            int ty = t >> 2, xt = t & 3;
            int m0 = (y0 + ty) * 64 + xt * 16;
            float lam[4];
#pragma unroll
            for (int r = 0; r < 4; r++) lam[r] = acc[t][r] + sck_l[r];
            float po[4] = {0.f, 0.f, 0.f, 0.f};
#pragma unroll
            for (int i = 0; i < 16; i++) {          // i = r*4 + n ; channel c = kg*16+i
                float qv = qslab[(size_t)(kg * 16 + i) * MPIX + m0 + px];
                po[i & 3] = fmaf(qv, lam[i >> 2], po[i & 3]);
            }
#pragma unroll
            for (int n = 0; n < 4; n++) {
                po[n] += __shfl_xor(po[n], 16);
                po[n] += __shfl_xor(po[n], 32);
            }
            float sv = (kg == 0) ? po[0] : (kg == 1) ? po[1] : (kg == 2) ? po[2] : po[3];
            ob[(size_t)(kg * 64 + vc) * MPIX + m0 + px] = sv;
        }
    }
}

// ---------------- launch ----------------
extern "C" void kernel_launch(void* const* d_in, const int* in_sizes, int n_in,
                              void* d_out, int out_size, void* d_ws, size_t ws_size,
                              hipStream_t stream) {
    const float* x      = (const float*)d_in[0];
    const float* w_qkv  = (const float*)d_in[1];
    const float* gq     = (const float*)d_in[2];
    const float* bq     = (const float*)d_in[3];
    const float* gv     = (const float*)d_in[4];
    const float* bv     = (const float*)d_in[5];
    const float* wl     = (const float*)d_in[6];
    const float* bl     = (const float*)d_in[7];
    float* out = (float*)d_out;

    float* ws     = (float*)d_ws;
    float* qkv    = ws;                    // 16*144*4096 = 9,437,184
    float* p      = qkv + 9437184;         // 1,048,576
    float* part   = p + 1048576;           // 4,096
    float* ascale = part + 4096;           // 128
    float* dshift = ascale + 128;          // 128
    float* clpart = dshift + 128;          // 262,144
    float* clb    = clpart + 262144;       // 16,384
    short* wfrag  = (short*)(clb + 16384); // 23552 halfs = 47,104 B

    gemm_qkv<<<dim3(16, 3, 16), 256, 0, stream>>>(x, w_qkv, qkv);
    stats_partial<<<dim3(128, 16), 256, 0, stream>>>(qkv, part);
    stats_finalize<<<1, 128, 0, stream>>>(part, gq, bq, gv, bv, ascale, dshift);
    softmax_k<<<256, 256, 0, stream>>>(qkv, p);
    cl_partial<<<dim3(16, 16), 256, 0, stream>>>(qkv, p, ascale, dshift, clpart);
    cl_reduce<<<16, 256, 0, stream>>>(clpart, clb);
    bn_q<<<dim3(64, 16), 256, 0, stream>>>(qkv, ascale, dshift);
    wfrag_prep<<<92, 256, 0, stream>>>(wl, wfrag);
    lambda_main<<<dim3(64, 16), 256, 0, stream>>>(qkv, ascale, dshift, clb, wfrag, bl, out);
}